// Round 14
// baseline (4472.978 us; speedup 1.0000x reference)
//
#include <hip/hip_runtime.h>

#define NNODE 50000   // both N_U and N_I
#define NE    200000
#define H     8
#define DH    32
#define D     256
#define L     2
#define DIN   128
#define DOUT  16

// ---------------- float <-> order-preserving uint encoding for atomicMax ----
__device__ __forceinline__ unsigned encodeF(float f) {
    unsigned u = __float_as_uint(f);
    return (u & 0x80000000u) ? ~u : (u | 0x80000000u);
}
__device__ __forceinline__ float decodeF(unsigned u) {
    unsigned v = (u & 0x80000000u) ? (u & 0x7FFFFFFFu) : ~u;
    return __uint_as_float(v);
}

// ---------------- fused relation weights: WF = W * blockdiag(wrel) ----------
// blockIdx.x = idx = (l*2+et)*2 + which   (which: 0 = att(k), 1 = msg(v))
// blockIdx.y = row block (64 rows each)
__global__ __launch_bounds__(256) void fuse_weights(
    const float* __restrict__ Wk, const float* __restrict__ bk,
    const float* __restrict__ Wv, const float* __restrict__ bv,
    const float* __restrict__ w_att, const float* __restrict__ w_msg,
    float* __restrict__ WF, float* __restrict__ bF) {
    int idx = blockIdx.x;          // 0..7
    int which = idx & 1;
    int le = idx >> 1;             // l*2+et
    int c = threadIdx.x;           // output column 0..255
    int h = c >> 5, cc = c & 31;
    const float* Wsrc = (which ? Wv : Wk) + (size_t)le * D * D;
    const float* bsrc = (which ? bv : bk) + (size_t)le * D;
    const float* wrel = (which ? w_msg : w_att) + ((size_t)(le * H + h) * DH) * DH + cc;
    float* WFo = WF + (size_t)idx * D * D;

    for (int d0 = 0; d0 < 64; ++d0) {
        int d = blockIdx.y * 64 + d0;
        const float* wrow = Wsrc + (size_t)d * D + h * DH;
        float s = 0.f;
#pragma unroll 8
        for (int j = 0; j < DH; ++j) s = fmaf(wrow[j], wrel[j * DH], s);
        WFo[(size_t)d * D + c] = s;
    }
    if (blockIdx.y == 0) {
        const float* brow = bsrc + h * DH;
        float s = 0.f;
#pragma unroll 8
        for (int j = 0; j < DH; ++j) s = fmaf(brow[j], wrel[j * DH], s);
        bF[(size_t)idx * D + c] = s;
    }
}

// ---------------- fp32 GEMM:  Y(M x 256) = X(M x K) @ W(K x 256) + bias -----
// tile 128x64, 256 threads, each thread 8x4 outputs
__global__ __launch_bounds__(256) void gemm_f32(
    const float* __restrict__ X, const float* __restrict__ W,
    const float* __restrict__ bias, float* __restrict__ Y,
    int M, int K) {
    __shared__ float sX[16][132];   // [k][row], padded (132 => 2-way max)
    __shared__ float sW[16][64];    // [k][col]
    const int bm = blockIdx.x * 128;
    const int bn = blockIdx.y * 64;
    const int tid = threadIdx.x;
    const int tx = tid & 15;        // col group (4 cols)
    const int ty = tid >> 4;        // row group (8 rows)
    float acc[8][4] = {};

    for (int k0 = 0; k0 < K; k0 += 16) {
        // X tile: 128 rows x 16 k, float4 loads, transposed store to LDS
#pragma unroll
        for (int i = 0; i < 2; ++i) {
            int r = (tid >> 2) + 64 * i;       // 0..127
            int row = bm + r;
            float4 v = make_float4(0.f, 0.f, 0.f, 0.f);
            if (row < M) v = *(const float4*)&X[(size_t)row * K + k0 + (tid & 3) * 4];
            int kc = (tid & 3) * 4;
            sX[kc + 0][r] = v.x; sX[kc + 1][r] = v.y;
            sX[kc + 2][r] = v.z; sX[kc + 3][r] = v.w;
        }
        // W tile: 16 k x 64 cols, one float4 per thread
        {
            int kk = tid >> 4;
            int c4 = (tid & 15) * 4;
            *(float4*)&sW[kk][c4] = *(const float4*)&W[(size_t)(k0 + kk) * D + bn + c4];
        }
        __syncthreads();
#pragma unroll
        for (int kk = 0; kk < 16; ++kk) {
            float4 xv0 = *(const float4*)&sX[kk][ty * 8];
            float4 xv1 = *(const float4*)&sX[kk][ty * 8 + 4];
            float4 wv  = *(const float4*)&sW[kk][tx * 4];
            float xr[8] = {xv0.x, xv0.y, xv0.z, xv0.w, xv1.x, xv1.y, xv1.z, xv1.w};
            float wr[4] = {wv.x, wv.y, wv.z, wv.w};
#pragma unroll
            for (int i = 0; i < 8; ++i)
#pragma unroll
                for (int j = 0; j < 4; ++j)
                    acc[i][j] = fmaf(xr[i], wr[j], acc[i][j]);
        }
        __syncthreads();
    }
    float4 bv4 = *(const float4*)&bias[bn + tx * 4];
#pragma unroll
    for (int i = 0; i < 8; ++i) {
        int row = bm + ty * 8 + i;
        if (row < M) {
            float4 o;
            o.x = acc[i][0] + bv4.x; o.y = acc[i][1] + bv4.y;
            o.z = acc[i][2] + bv4.z; o.w = acc[i][3] + bv4.w;
            *(float4*)&Y[(size_t)row * D + bn + tx * 4] = o;
        }
    }
}

// ---------------- edge phase 1: scores + segment max ------------------------
// one wave per edge, 4 edges per block
__global__ __launch_bounds__(256) void edge_score(
    const float* __restrict__ kp, const float* __restrict__ q,
    const int* __restrict__ src, const int* __restrict__ dst,
    const float* __restrict__ mup,      // 8 floats (this l,et)
    float* __restrict__ sc, unsigned* __restrict__ mEnc) {
    int e = blockIdx.x * 4 + (threadIdx.x >> 6);
    if (e >= NE) return;
    int lane = threadIdx.x & 63;
    int s = src[e], d = dst[e];
    float4 kv = *(const float4*)&kp[(size_t)s * D + lane * 4];
    float4 qv = *(const float4*)&q[(size_t)d * D + lane * 4];
    float p = kv.x * qv.x + kv.y * qv.y + kv.z * qv.z + kv.w * qv.w;
    p += __shfl_xor(p, 1);
    p += __shfl_xor(p, 2);
    p += __shfl_xor(p, 4);
    int head = lane >> 3;
    if ((lane & 7) == 0) {
        float val = p * mup[head] * 0.17677669529663687f;  // 1/sqrt(32)
        sc[(size_t)e * H + head] = val;
        atomicMax(&mEnc[(size_t)d * H + head], encodeF(val));
    }
}

// ---------------- edge phase 2: exp + denominator ---------------------------
__global__ __launch_bounds__(256) void edge_expden(
    float* __restrict__ sc, const int* __restrict__ dst,
    const unsigned* __restrict__ mEnc, float* __restrict__ den) {
    int i = blockIdx.x * 256 + threadIdx.x;
    if (i >= NE * H) return;
    int e = i >> 3, h = i & 7;
    int d = dst[e];
    float m = decodeF(mEnc[(size_t)d * H + h]);
    float ex = expf(sc[i] - m);
    sc[i] = ex;
    atomicAdd(&den[(size_t)d * H + h], ex);
}

// ---------------- edge phase 3: weighted scatter-aggregate ------------------
__global__ __launch_bounds__(256) void edge_agg(
    const float* __restrict__ vp, const float* __restrict__ ex,
    const float* __restrict__ den, const int* __restrict__ src,
    const int* __restrict__ dst, float* __restrict__ agg) {
    int e = blockIdx.x * 4 + (threadIdx.x >> 6);
    if (e >= NE) return;
    int lane = threadIdx.x & 63;
    int s = src[e], d = dst[e];
    int head = lane >> 3;
    float a = ex[(size_t)e * H + head] / den[(size_t)d * H + head];
    float4 v = *(const float4*)&vp[(size_t)s * D + lane * 4];
    float* base = &agg[(size_t)d * D + lane * 4];
    atomicAdd(base + 0, a * v.x);
    atomicAdd(base + 1, a * v.y);
    atomicAdd(base + 2, a * v.z);
    atomicAdd(base + 3, a * v.w);
}

// ---------------- classifier: out = hu @ Wc + bc ----------------------------
__global__ __launch_bounds__(256) void classifier_k(
    const float* __restrict__ hu, const float* __restrict__ Wc,
    const float* __restrict__ bc, float* __restrict__ out) {
    int tid = threadIdx.x;
    int row = blockIdx.x * 16 + (tid >> 4);
    int c = tid & 15;
    if (row >= NNODE) return;
    const float* hrow = hu + (size_t)row * D;
    float s = bc[c];
#pragma unroll 8
    for (int k = 0; k < D; ++k) s = fmaf(hrow[k], Wc[k * DOUT + c], s);
    out[(size_t)row * DOUT + c] = s;
}

// ---------------------------------------------------------------------------
extern "C" void kernel_launch(void* const* d_in, const int* in_sizes, int n_in,
                              void* d_out, int out_size, void* d_ws, size_t ws_size,
                              hipStream_t stream) {
    const float* feat_user = (const float*)d_in[0];
    const float* feat_item = (const float*)d_in[1];
    const float* Win_user  = (const float*)d_in[2];
    const float* bin_user  = (const float*)d_in[3];
    const float* Win_item  = (const float*)d_in[4];
    const float* bin_item  = (const float*)d_in[5];
    const float* Wk  = (const float*)d_in[6];
    const float* bk  = (const float*)d_in[7];
    const float* Wq  = (const float*)d_in[8];
    const float* bq  = (const float*)d_in[9];
    const float* Wv  = (const float*)d_in[10];
    const float* bv  = (const float*)d_in[11];
    const float* w_att = (const float*)d_in[12];
    const float* w_msg = (const float*)d_in[13];
    const float* mu  = (const float*)d_in[14];
    const float* Wc  = (const float*)d_in[15];
    const float* bc  = (const float*)d_in[16];
    const int* src_ui = (const int*)d_in[17];
    const int* dst_ui = (const int*)d_in[18];
    const int* src_iu = (const int*)d_in[19];
    const int* dst_iu = (const int*)d_in[20];
    float* out = (float*)d_out;

    char* ws = (char*)d_ws;
    size_t off = 0;
    auto alloc = [&](size_t elems) -> float* {
        float* p = (float*)(ws + off);
        off += (elems * 4 + 255) & ~(size_t)255;
        return p;
    };
    // minimal live set: hu (in-place updated), hi (double-buffered), q, k/v
    float* HU   = alloc((size_t)NNODE * D);   // hu; new_hu aggregates in place
    float* HIa  = alloc((size_t)NNODE * D);   // hi
    float* HIb  = alloc((size_t)NNODE * D);   // new_hi scratch (swapped per layer)
    float* Pq   = alloc((size_t)NNODE * D);   // q projection (reused per etype)
    float* Pkv  = alloc((size_t)NNODE * D);   // k-proj, then v-proj (reused)
    float* WF   = alloc((size_t)8 * D * D);
    float* bF   = alloc((size_t)8 * D);
    float* sc   = alloc((size_t)NE * H);
    unsigned* mEnc = (unsigned*)alloc((size_t)NNODE * H);
    float* den  = alloc((size_t)NNODE * H);

    if (ws_size < off) return;   // launch-constant guard: clean FAIL, not a GPU fault

    dim3 gemmGrid((NNODE + 127) / 128, D / 64);
    dim3 blk(256);

    // fused relation weights (cheap, recomputed every call)
    hipLaunchKernelGGL(fuse_weights, dim3(8, 4), blk, 0, stream,
                       Wk, bk, Wv, bv, w_att, w_msg, WF, bF);

    // fc_in
    hipLaunchKernelGGL(gemm_f32, gemmGrid, blk, 0, stream,
                       feat_user, Win_user, bin_user, HU, NNODE, DIN);
    hipLaunchKernelGGL(gemm_f32, gemmGrid, blk, 0, stream,
                       feat_item, Win_item, bin_item, HIa, NNODE, DIN);

    float* hi   = HIa;
    float* hisc = HIb;

    for (int l = 0; l < L; ++l) {
        int le0 = l * 2 + 0, le1 = l * 2 + 1;

        // ---- etype 0: user -> item (k,v from hu; q from hi; dst = item) ----
        hipLaunchKernelGGL(gemm_f32, gemmGrid, blk, 0, stream,
                           hi, Wq + (size_t)(l * 2 + 1) * D * D, bq + (l * 2 + 1) * D,
                           Pq, NNODE, D);
        hipLaunchKernelGGL(gemm_f32, gemmGrid, blk, 0, stream,
                           HU, WF + (size_t)(le0 * 2 + 0) * D * D, bF + (le0 * 2 + 0) * D,
                           Pkv, NNODE, D);                       // k' = hu @ Wk·att
        hipMemsetAsync(mEnc, 0, (size_t)NNODE * H * 4, stream);
        hipMemsetAsync(den, 0, (size_t)NNODE * H * 4, stream);
        hipLaunchKernelGGL(edge_score, dim3(NE / 4), blk, 0, stream,
                           Pkv, Pq, src_ui, dst_ui, mu + l * 16 + 0, sc, mEnc);
        hipLaunchKernelGGL(edge_expden, dim3(NE * H / 256), blk, 0, stream,
                           sc, dst_ui, mEnc, den);
        hipLaunchKernelGGL(gemm_f32, gemmGrid, blk, 0, stream,
                           HU, WF + (size_t)(le0 * 2 + 1) * D * D, bF + (le0 * 2 + 1) * D,
                           Pkv, NNODE, D);                       // v' = hu @ Wv·msg
        hipMemsetAsync(hisc, 0, (size_t)NNODE * D * 4, stream);
        hipLaunchKernelGGL(edge_agg, dim3(NE / 4), blk, 0, stream,
                           Pkv, sc, den, src_ui, dst_ui, hisc);  // new_hi

        // ---- etype 1: item -> user (k,v from hi; q from hu; dst = user) ----
        hipLaunchKernelGGL(gemm_f32, gemmGrid, blk, 0, stream,
                           HU, Wq + (size_t)(l * 2 + 0) * D * D, bq + (l * 2 + 0) * D,
                           Pq, NNODE, D);                        // last read of HU
        hipLaunchKernelGGL(gemm_f32, gemmGrid, blk, 0, stream,
                           hi, WF + (size_t)(le1 * 2 + 0) * D * D, bF + (le1 * 2 + 0) * D,
                           Pkv, NNODE, D);
        hipMemsetAsync(mEnc, 0, (size_t)NNODE * H * 4, stream);
        hipMemsetAsync(den, 0, (size_t)NNODE * H * 4, stream);
        hipLaunchKernelGGL(edge_score, dim3(NE / 4), blk, 0, stream,
                           Pkv, Pq, src_iu, dst_iu, mu + l * 16 + 8, sc, mEnc);
        hipLaunchKernelGGL(edge_expden, dim3(NE * H / 256), blk, 0, stream,
                           sc, dst_iu, mEnc, den);
        hipLaunchKernelGGL(gemm_f32, gemmGrid, blk, 0, stream,
                           hi, WF + (size_t)(le1 * 2 + 1) * D * D, bF + (le1 * 2 + 1) * D,
                           Pkv, NNODE, D);                       // last read of hi
        hipMemsetAsync(HU, 0, (size_t)NNODE * D * 4, stream);    // HU dead -> reuse
        hipLaunchKernelGGL(edge_agg, dim3(NE / 4), blk, 0, stream,
                           Pkv, sc, den, src_iu, dst_iu, HU);    // new_hu in place

        float* t = hi; hi = hisc; hisc = t;                      // hi <- new_hi
    }

    hipLaunchKernelGGL(classifier_k, dim3((NNODE + 15) / 16), blk, 0, stream,
                       HU, Wc, bc, out);
}

// Round 16
// 1934.764 us; speedup vs baseline: 2.3119x; 2.3119x over previous
//
#include <hip/hip_runtime.h>

#define NNODE 50000   // both N_U and N_I
#define NE    200000
#define H     8
#define DH    32
#define D     256
#define L     2
#define DIN   128
#define DOUT  16
#define NBLK  196     // ceil(NNODE/256)

// ---------------- fused relation weights: WF = W * blockdiag(wrel) ----------
__global__ __launch_bounds__(256) void fuse_weights(
    const float* __restrict__ Wk, const float* __restrict__ bk,
    const float* __restrict__ Wv, const float* __restrict__ bv,
    const float* __restrict__ w_att, const float* __restrict__ w_msg,
    float* __restrict__ WF, float* __restrict__ bF) {
    int idx = blockIdx.x;          // 0..7 = (l*2+et)*2 + which
    int which = idx & 1;
    int le = idx >> 1;
    int c = threadIdx.x;
    int h = c >> 5, cc = c & 31;
    const float* Wsrc = (which ? Wv : Wk) + (size_t)le * D * D;
    const float* bsrc = (which ? bv : bk) + (size_t)le * D;
    const float* wrel = (which ? w_msg : w_att) + ((size_t)(le * H + h) * DH) * DH + cc;
    float* WFo = WF + (size_t)idx * D * D;

    for (int d0 = 0; d0 < 64; ++d0) {
        int d = blockIdx.y * 64 + d0;
        const float* wrow = Wsrc + (size_t)d * D + h * DH;
        float s = 0.f;
#pragma unroll 8
        for (int j = 0; j < DH; ++j) s = fmaf(wrow[j], wrel[j * DH], s);
        WFo[(size_t)d * D + c] = s;
    }
    if (blockIdx.y == 0) {
        const float* brow = bsrc + h * DH;
        float s = 0.f;
#pragma unroll 8
        for (int j = 0; j < DH; ++j) s = fmaf(brow[j], wrel[j * DH], s);
        bF[(size_t)idx * D + c] = s;
    }
}

// ---------------- fp32 GEMM:  Y(M x 256) = X(M x K) @ W(K x 256) + bias -----
__global__ __launch_bounds__(256) void gemm_f32(
    const float* __restrict__ X, const float* __restrict__ W,
    const float* __restrict__ bias, float* __restrict__ Y,
    int M, int K) {
    __shared__ float sX[16][132];
    __shared__ float sW[16][64];
    const int bm = blockIdx.x * 128;
    const int bn = blockIdx.y * 64;
    const int tid = threadIdx.x;
    const int tx = tid & 15;
    const int ty = tid >> 4;
    float acc[8][4] = {};

    for (int k0 = 0; k0 < K; k0 += 16) {
#pragma unroll
        for (int i = 0; i < 2; ++i) {
            int r = (tid >> 2) + 64 * i;
            int row = bm + r;
            float4 v = make_float4(0.f, 0.f, 0.f, 0.f);
            if (row < M) v = *(const float4*)&X[(size_t)row * K + k0 + (tid & 3) * 4];
            int kc = (tid & 3) * 4;
            sX[kc + 0][r] = v.x; sX[kc + 1][r] = v.y;
            sX[kc + 2][r] = v.z; sX[kc + 3][r] = v.w;
        }
        {
            int kk = tid >> 4;
            int c4 = (tid & 15) * 4;
            *(float4*)&sW[kk][c4] = *(const float4*)&W[(size_t)(k0 + kk) * D + bn + c4];
        }
        __syncthreads();
#pragma unroll
        for (int kk = 0; kk < 16; ++kk) {
            float4 xv0 = *(const float4*)&sX[kk][ty * 8];
            float4 xv1 = *(const float4*)&sX[kk][ty * 8 + 4];
            float4 wv  = *(const float4*)&sW[kk][tx * 4];
            float xr[8] = {xv0.x, xv0.y, xv0.z, xv0.w, xv1.x, xv1.y, xv1.z, xv1.w};
            float wr[4] = {wv.x, wv.y, wv.z, wv.w};
#pragma unroll
            for (int i = 0; i < 8; ++i)
#pragma unroll
                for (int j = 0; j < 4; ++j)
                    acc[i][j] = fmaf(xr[i], wr[j], acc[i][j]);
        }
        __syncthreads();
    }
    float4 bv4 = *(const float4*)&bias[bn + tx * 4];
#pragma unroll
    for (int i = 0; i < 8; ++i) {
        int row = bm + ty * 8 + i;
        if (row < M) {
            float4 o;
            o.x = acc[i][0] + bv4.x; o.y = acc[i][1] + bv4.y;
            o.z = acc[i][2] + bv4.z; o.w = acc[i][3] + bv4.w;
            *(float4*)&Y[(size_t)row * D + bn + tx * 4] = o;
        }
    }
}

// ---------------- CSR build: histogram -> 2-level scan -> slot scatter ------
__global__ __launch_bounds__(256) void hist_k(const int* __restrict__ dst,
                                              int* __restrict__ cnt) {
    int e = blockIdx.x * 256 + threadIdx.x;
    if (e < NE) atomicAdd(&cnt[dst[e]], 1);
}

__global__ __launch_bounds__(256) void bsum_k(const int* __restrict__ cnt,
                                              int* __restrict__ bsum) {
    __shared__ int s[256];
    int i = blockIdx.x * 256 + threadIdx.x;
    s[threadIdx.x] = (i < NNODE) ? cnt[i] : 0;
    __syncthreads();
    for (int st = 128; st > 0; st >>= 1) {
        if (threadIdx.x < st) s[threadIdx.x] += s[threadIdx.x + st];
        __syncthreads();
    }
    if (threadIdx.x == 0) bsum[blockIdx.x] = s[0];
}

__global__ __launch_bounds__(256) void bscan_k(int* __restrict__ bsum) {
    // exclusive scan of NBLK (<=256) block sums, single block
    __shared__ int s[256];
    int t = threadIdx.x;
    s[t] = (t < NBLK) ? bsum[t] : 0;
    __syncthreads();
    for (int off = 1; off < 256; off <<= 1) {
        int x = (t >= off) ? s[t - off] : 0;
        __syncthreads();
        s[t] += x;
        __syncthreads();
    }
    if (t < NBLK) bsum[t] = (t == 0) ? 0 : s[t - 1];
}

__global__ __launch_bounds__(256) void rowptr_k(const int* __restrict__ cnt,
                                                const int* __restrict__ bsum,
                                                int* __restrict__ rowptr) {
    __shared__ int s[256];
    int t = threadIdx.x;
    int i = blockIdx.x * 256 + t;
    int v = (i < NNODE) ? cnt[i] : 0;
    s[t] = v;
    __syncthreads();
    for (int off = 1; off < 256; off <<= 1) {
        int x = (t >= off) ? s[t - off] : 0;
        __syncthreads();
        s[t] += x;
        __syncthreads();
    }
    if (i < NNODE) rowptr[i] = bsum[blockIdx.x] + s[t] - v;  // exclusive
    if (blockIdx.x == 0 && t == 0) rowptr[NNODE] = NE;
}

__global__ __launch_bounds__(256) void scatter_k(const int* __restrict__ dst,
                                                 const int* __restrict__ rowptr,
                                                 int* __restrict__ cur,
                                                 int* __restrict__ eord) {
    int e = blockIdx.x * 256 + threadIdx.x;
    if (e < NE) {
        int d = dst[e];
        int slot = atomicAdd(&cur[d], 1);
        eord[rowptr[d] + slot] = e;
    }
}

// ---------------- edge scores (no atomics): sc[e][h] ------------------------
__global__ __launch_bounds__(256) void edge_score(
    const float* __restrict__ kp, const float* __restrict__ q,
    const int* __restrict__ src, const int* __restrict__ dst,
    const float* __restrict__ mup, float* __restrict__ sc) {
    int e = blockIdx.x * 4 + (threadIdx.x >> 6);
    if (e >= NE) return;
    int lane = threadIdx.x & 63;
    int s = src[e], d = dst[e];
    float4 kv = *(const float4*)&kp[(size_t)s * D + lane * 4];
    float4 qv = *(const float4*)&q[(size_t)d * D + lane * 4];
    float p = kv.x * qv.x + kv.y * qv.y + kv.z * qv.z + kv.w * qv.w;
    p += __shfl_xor(p, 1);
    p += __shfl_xor(p, 2);
    p += __shfl_xor(p, 4);
    int head = lane >> 3;
    if ((lane & 7) == 0)
        sc[(size_t)e * H + head] = p * mup[head] * 0.17677669529663687f; // 1/sqrt(32)
}

// ---------------- fused per-node softmax + aggregate (no atomics) -----------
// one wave per dst node; lane owns 4 output floats; head = lane>>3
__global__ __launch_bounds__(256) void node_agg(
    const float* __restrict__ vp, const float* __restrict__ sc,
    const int* __restrict__ srcArr, const int* __restrict__ rowptr,
    const int* __restrict__ eord, float* __restrict__ aggout) {
    int d = blockIdx.x * 4 + (threadIdx.x >> 6);
    if (d >= NNODE) return;
    int lane = threadIdx.x & 63;
    int head = lane >> 3;
    int beg = rowptr[d], end = rowptr[d + 1];
    float4 acc = make_float4(0.f, 0.f, 0.f, 0.f);
    if (beg == end) {                       // no incoming edges -> zeros
        *(float4*)&aggout[(size_t)d * D + lane * 4] = acc;
        return;
    }
    float m = -3.402823466e38f;
    for (int i = beg; i < end; ++i) {
        int e = eord[i];
        m = fmaxf(m, sc[(size_t)e * H + head]);
    }
    float sum = 0.f;
    for (int i = beg; i < end; ++i) {
        int e = eord[i];
        float w = expf(sc[(size_t)e * H + head] - m);
        sum += w;
        int s = srcArr[e];
        float4 v = *(const float4*)&vp[(size_t)s * D + lane * 4];
        acc.x = fmaf(w, v.x, acc.x);
        acc.y = fmaf(w, v.y, acc.y);
        acc.z = fmaf(w, v.z, acc.z);
        acc.w = fmaf(w, v.w, acc.w);
    }
    float inv = 1.f / sum;                  // sum >= 1 (max term contributes 1)
    acc.x *= inv; acc.y *= inv; acc.z *= inv; acc.w *= inv;
    *(float4*)&aggout[(size_t)d * D + lane * 4] = acc;
}

// ---------------- classifier: out = hu @ Wc + bc ----------------------------
__global__ __launch_bounds__(256) void classifier_k(
    const float* __restrict__ hu, const float* __restrict__ Wc,
    const float* __restrict__ bc, float* __restrict__ out) {
    int tid = threadIdx.x;
    int row = blockIdx.x * 16 + (tid >> 4);
    int c = tid & 15;
    if (row >= NNODE) return;
    const float* hrow = hu + (size_t)row * D;
    float s = bc[c];
#pragma unroll 8
    for (int k = 0; k < D; ++k) s = fmaf(hrow[k], Wc[k * DOUT + c], s);
    out[(size_t)row * DOUT + c] = s;
}

// ---------------------------------------------------------------------------
extern "C" void kernel_launch(void* const* d_in, const int* in_sizes, int n_in,
                              void* d_out, int out_size, void* d_ws, size_t ws_size,
                              hipStream_t stream) {
    const float* feat_user = (const float*)d_in[0];
    const float* feat_item = (const float*)d_in[1];
    const float* Win_user  = (const float*)d_in[2];
    const float* bin_user  = (const float*)d_in[3];
    const float* Win_item  = (const float*)d_in[4];
    const float* bin_item  = (const float*)d_in[5];
    const float* Wk  = (const float*)d_in[6];
    const float* bk  = (const float*)d_in[7];
    const float* Wq  = (const float*)d_in[8];
    const float* bq  = (const float*)d_in[9];
    const float* Wv  = (const float*)d_in[10];
    const float* bv  = (const float*)d_in[11];
    const float* w_att = (const float*)d_in[12];
    const float* w_msg = (const float*)d_in[13];
    const float* mu  = (const float*)d_in[14];
    const float* Wc  = (const float*)d_in[15];
    const float* bc  = (const float*)d_in[16];
    const int* src_ui = (const int*)d_in[17];
    const int* dst_ui = (const int*)d_in[18];
    const int* src_iu = (const int*)d_in[19];
    const int* dst_iu = (const int*)d_in[20];
    float* out = (float*)d_out;

    char* ws = (char*)d_ws;
    size_t off = 0;
    auto alloc = [&](size_t elems) -> float* {
        float* p = (float*)(ws + off);
        off += (elems * 4 + 255) & ~(size_t)255;
        return p;
    };
    float* HU   = alloc((size_t)NNODE * D);
    float* HIa  = alloc((size_t)NNODE * D);
    float* HIb  = alloc((size_t)NNODE * D);
    float* Pq   = alloc((size_t)NNODE * D);
    float* Pkv  = alloc((size_t)NNODE * D);
    float* WF   = alloc((size_t)8 * D * D);
    float* bF   = alloc((size_t)8 * D);
    float* sc   = alloc((size_t)NE * H);
    int* rp0  = (int*)alloc(NNODE + 1);   // CSR for dst_ui (items)
    int* eo0  = (int*)alloc(NE);
    int* rp1  = (int*)alloc(NNODE + 1);   // CSR for dst_iu (users)
    int* eo1  = (int*)alloc(NE);
    int* cnt  = (int*)alloc(NNODE);       // histogram, then scatter cursor
    int* bsum = (int*)alloc(256);

    if (ws_size < off) return;   // clean FAIL, not a GPU fault

    dim3 gemmGrid((NNODE + 127) / 128, D / 64);
    dim3 blk(256);
    const int gE = (NE + 255) / 256;      // 782

    hipLaunchKernelGGL(fuse_weights, dim3(8, 4), blk, 0, stream,
                       Wk, bk, Wv, bv, w_att, w_msg, WF, bF);

    // ---- build the two CSRs (edges constant across layers) ----
    auto build_csr = [&](const int* dst, int* rp, int* eo) {
        hipMemsetAsync(cnt, 0, (size_t)NNODE * 4, stream);
        hipLaunchKernelGGL(hist_k, dim3(gE), blk, 0, stream, dst, cnt);
        hipLaunchKernelGGL(bsum_k, dim3(NBLK), blk, 0, stream, cnt, bsum);
        hipLaunchKernelGGL(bscan_k, dim3(1), blk, 0, stream, bsum);
        hipLaunchKernelGGL(rowptr_k, dim3(NBLK), blk, 0, stream, cnt, bsum, rp);
        hipMemsetAsync(cnt, 0, (size_t)NNODE * 4, stream);
        hipLaunchKernelGGL(scatter_k, dim3(gE), blk, 0, stream, dst, rp, cnt, eo);
    };
    build_csr(dst_ui, rp0, eo0);
    build_csr(dst_iu, rp1, eo1);

    // ---- fc_in ----
    hipLaunchKernelGGL(gemm_f32, gemmGrid, blk, 0, stream,
                       feat_user, Win_user, bin_user, HU, NNODE, DIN);
    hipLaunchKernelGGL(gemm_f32, gemmGrid, blk, 0, stream,
                       feat_item, Win_item, bin_item, HIa, NNODE, DIN);

    float* hi   = HIa;
    float* hisc = HIb;
    const int gN = (NNODE + 3) / 4;       // node_agg grid

    for (int l = 0; l < L; ++l) {
        int le0 = l * 2 + 0, le1 = l * 2 + 1;

        // ---- etype 0: user -> item (k,v from HU; q from hi; dst = item) ----
        hipLaunchKernelGGL(gemm_f32, gemmGrid, blk, 0, stream,
                           hi, Wq + (size_t)(l * 2 + 1) * D * D, bq + (l * 2 + 1) * D,
                           Pq, NNODE, D);
        hipLaunchKernelGGL(gemm_f32, gemmGrid, blk, 0, stream,
                           HU, WF + (size_t)(le0 * 2 + 0) * D * D, bF + (le0 * 2 + 0) * D,
                           Pkv, NNODE, D);                       // k'
        hipLaunchKernelGGL(edge_score, dim3(NE / 4), blk, 0, stream,
                           Pkv, Pq, src_ui, dst_ui, mu + l * 16 + 0, sc);
        hipLaunchKernelGGL(gemm_f32, gemmGrid, blk, 0, stream,
                           HU, WF + (size_t)(le0 * 2 + 1) * D * D, bF + (le0 * 2 + 1) * D,
                           Pkv, NNODE, D);                       // v' (after scores)
        hipLaunchKernelGGL(node_agg, dim3(gN), blk, 0, stream,
                           Pkv, sc, src_ui, rp0, eo0, hisc);     // new_hi

        // ---- etype 1: item -> user (k,v from hi; q from HU; dst = user) ----
        hipLaunchKernelGGL(gemm_f32, gemmGrid, blk, 0, stream,
                           HU, Wq + (size_t)(l * 2 + 0) * D * D, bq + (l * 2 + 0) * D,
                           Pq, NNODE, D);                        // last read of HU
        hipLaunchKernelGGL(gemm_f32, gemmGrid, blk, 0, stream,
                           hi, WF + (size_t)(le1 * 2 + 0) * D * D, bF + (le1 * 2 + 0) * D,
                           Pkv, NNODE, D);
        hipLaunchKernelGGL(edge_score, dim3(NE / 4), blk, 0, stream,
                           Pkv, Pq, src_iu, dst_iu, mu + l * 16 + 8, sc);
        hipLaunchKernelGGL(gemm_f32, gemmGrid, blk, 0, stream,
                           hi, WF + (size_t)(le1 * 2 + 1) * D * D, bF + (le1 * 2 + 1) * D,
                           Pkv, NNODE, D);                       // last read of hi
        hipLaunchKernelGGL(node_agg, dim3(gN), blk, 0, stream,
                           Pkv, sc, src_iu, rp1, eo1, HU);       // new_hu in place

        float* t = hi; hi = hisc; hisc = t;
    }

    hipLaunchKernelGGL(classifier_k, dim3((NNODE + 15) / 16), blk, 0, stream,
                       HU, Wc, bc, out);
}